// Round 19
// baseline (179.187 us; speedup 1.0000x reference)
//
#include <hip/hip_runtime.h>

typedef short bf16x8 __attribute__((ext_vector_type(8)));
typedef float f32x4 __attribute__((ext_vector_type(4)));

constexpr int Bb = 8, Ntok = 2048, Cdim = 768, Ddim = 384, Mrows = 16384;
constexpr int KSPLIT = 4;   // MT GEMM K-slices per batch

__device__ __forceinline__ void gload16(const void* g, void* l) {
    __builtin_amdgcn_global_load_lds(
        (const __attribute__((address_space(1))) unsigned int*)g,
        (__attribute__((address_space(3))) unsigned int*)l, 16, 0, 0);
}

// Hand-rolled RNE fp32->bf16 (finite inputs only)
__device__ __forceinline__ unsigned short f2bf(float x) {
    union { float f; unsigned u; } c; c.f = x;
    const unsigned r = c.u + 0x7fffu + ((c.u >> 16) & 1u);
    return (unsigned short)(r >> 16);
}
__device__ __forceinline__ float bf2f(unsigned short u) {
    union { unsigned u; float f; } c; c.u = (unsigned)u << 16;
    return c.f;
}
__device__ __forceinline__ uint4 cvt8(const float4 a, const float4 b) {
    union { unsigned short u[8]; uint4 q; } r;
    r.u[0] = f2bf(a.x); r.u[1] = f2bf(a.y); r.u[2] = f2bf(a.z); r.u[3] = f2bf(a.w);
    r.u[4] = f2bf(b.x); r.u[5] = f2bf(b.y); r.u[6] = f2bf(b.z); r.u[7] = f2bf(b.w);
    return r.q;
}

// Single barrier per K-step (3-deep LDS). No sched_barrier pins (m141).
#define BAR() do { asm volatile("" ::: "memory"); __builtin_amdgcn_s_barrier(); \
                   asm volatile("" ::: "memory"); } while (0)

// T1 bijective XCD swizzle (bid->XCD assumed bid%8 round-robin).
__device__ __forceinline__ void swz_xcd(int& bx, int& by, int& bz) {
    const int NN = gridDim.x, NY = gridDim.y;
    const int NP = NY * gridDim.z;
    const int lin = blockIdx.x + NN * (blockIdx.y + NY * blockIdx.z);
    const int x = lin & 7, g = lin >> 3;
    const int pan = x * (NP >> 3) + g / NN;
    bx = g % NN; by = pan % NY; bz = pan / NY;
}

// ---------------------------------------------------------------------------
// fused cast: blocks 0..575 weights; 576..6719 x_l; 6720..12863 x_h
// ---------------------------------------------------------------------------
__global__ __launch_bounds__(256) void cast_xw(
        const float* __restrict__ xl, const float* __restrict__ xh,
        const float* __restrict__ s0, const float* __restrict__ s1,
        const float* __restrict__ s2, const float* __restrict__ s3,
        unsigned short* __restrict__ dxl, unsigned short* __restrict__ dxh,
        unsigned short* __restrict__ d0, unsigned short* __restrict__ d1,
        unsigned short* __restrict__ d2, unsigned short* __restrict__ d3) {
    const int b = blockIdx.x;
    if (b < 576) {
        constexpr int n8 = 294912 / 8;
        const int i = b * 256 + threadIdx.x;
        const int sel = i / n8, loc = i - sel * n8;
        const float* s = sel == 0 ? s0 : sel == 1 ? s1 : sel == 2 ? s2 : s3;
        unsigned short* d = sel == 0 ? d0 : sel == 1 ? d1 : sel == 2 ? d2 : d3;
        const float4* s4 = (const float4*)s;
        ((uint4*)d)[loc] = cvt8(s4[2 * loc], s4[2 * loc + 1]);
    } else if (b < 6720) {
        const int i = (b - 576) * 256 + threadIdx.x;
        const float4* s4 = (const float4*)xl;
        ((uint4*)dxl)[i] = cvt8(s4[2 * i], s4[2 * i + 1]);
    } else {
        const int i = (b - 6720) * 256 + threadIdx.x;
        const float4* s4 = (const float4*)xh;
        ((uint4*)dxh)[i] = cvt8(s4[2 * i], s4[2 * i + 1]);
    }
}

// ---------------------------------------------------------------------------
// CONFLICT-FREE LDS LAYOUT (k-octet-major): tile stored as [4 kg][128 row][16B]
//   offset(row,kg) = kg*2048 + row*16.
// Staged via global_load_lds with wave w covering kg=w: per-wave dest =
// uniform base (w*2048 + half*1024) + lane*16 (m104-safe); global src is
// per-lane 16B at row (half*64+lane), k-octet w (per-lane scatter allowed).
// Fragment reads: 16 lanes read consecutive 16B rows -> canonical
// conflict-free ds_read_b128 pattern (was 8-way on 64B-row layout).
// ---------------------------------------------------------------------------

// FUSED input GEMMs: theta (384 blocks) + phi|g (768 blocks), one launch.
// 128x128 tile, BK=32, K=768 (nt=24). 3-deep LDS, one barrier per K-step.
__global__ __launch_bounds__(256) void gemm_inputs(
        const unsigned short* __restrict__ Xh, const unsigned short* __restrict__ Wth,
        const float* __restrict__ bth, unsigned short* __restrict__ Tout,
        const unsigned short* __restrict__ Xl, const unsigned short* __restrict__ Wpg,
        const float* __restrict__ bph, const float* __restrict__ bg,
        unsigned short* __restrict__ PGTout) {
    __shared__ __align__(16) char smem[49152];

    const int tid  = threadIdx.x;
    const int lane = tid & 63;
    const int w    = tid >> 6;
    const int wm   = w >> 1, wn = w & 1;

    const int bid = blockIdx.x;           // 0..1151
    const int x   = bid & 7;              // XCD
    const int g   = bid >> 3;             // 0..143
    const bool isTh = (g < 48);
    int bx, pan;
    if (isTh) { bx = g % 3;                 pan = x * 16 + g / 3; }
    else      { const int l = g - 48; bx = l % 6; pan = x * 16 + l / 6; }
    const int bm = pan * 128, bn = bx * 128;

    const unsigned short* A = isTh ? Xh : Xl;
    const unsigned short* B = isTh ? Wth : Wpg;
    constexpr int K = Cdim;                // 768
    constexpr int nt = K / 32;             // 24

    // staging offsets (k-octet-major layout)
    const int w8 = w * 8;                           // k elements per wave slot
    const unsigned dOff = w * 2048 + lane * 16;     // LDS dest for half 0
    const size_t aRow0 = (size_t)(bm + lane) * K + w8;
    const size_t aRow1 = (size_t)(bm + 64 + lane) * K + w8;
    const size_t bRow0 = (size_t)(bn + lane) * K + w8;
    const size_t bRow1 = (size_t)(bn + 64 + lane) * K + w8;

    f32x4 acc[4][4] = {};
    const int fr = lane & 15;
    const int kgOff = (lane >> 4) * 2048;           // fragment k-octet block

    auto bufA = [&](int p) -> char* { return smem + p * 8192; };
    auto bufB = [&](int p) -> char* { return smem + 24576 + p * 8192; };
    auto stage = [&](int p, int t) {
        const int k0 = t * 32;
        gload16(A + aRow0 + k0, bufA(p) + dOff);
        gload16(A + aRow1 + k0, bufA(p) + dOff + 1024);
        gload16(B + bRow0 + k0, bufB(p) + dOff);
        gload16(B + bRow1 + k0, bufB(p) + dOff + 1024);
    };
    auto compute = [&](int p) {
        const char* smA = bufA(p);
        const char* smB = bufB(p);
        bf16x8 fa[4], fb[4];
#pragma unroll
        for (int m = 0; m < 4; ++m)
            fa[m] = *(const bf16x8*)(smA + kgOff + (wm * 64 + m * 16 + fr) * 16);
#pragma unroll
        for (int n = 0; n < 4; ++n)
            fb[n] = *(const bf16x8*)(smB + kgOff + (wn * 64 + n * 16 + fr) * 16);
#pragma unroll
        for (int m = 0; m < 4; ++m)
#pragma unroll
            for (int n = 0; n < 4; ++n)
                acc[m][n] = __builtin_amdgcn_mfma_f32_16x16x32_bf16(fa[m], fb[n], acc[m][n], 0, 0, 0);
    };

    stage(0, 0); stage(1, 1);
    int p = 0;
    for (int t = 0; t < nt; ++t) {
        if (t + 1 < nt) asm volatile("s_waitcnt vmcnt(4)" ::: "memory");
        else            asm volatile("s_waitcnt vmcnt(0)" ::: "memory");
        BAR();
        if (t + 2 < nt) stage(p == 0 ? 2 : p - 1, t + 2);  // (t+2)%3
        compute(p);
        p = (p == 2) ? 0 : p + 1;
    }

    const int r0 = (lane >> 4) * 4;
    const int cc = lane & 15;

    if (isTh) {
        unsigned short* C = Tout;
#pragma unroll
        for (int n = 0; n < 4; ++n) {
            const int col = bn + wn * 64 + n * 16 + cc;
            const float bv = bth[col];
#pragma unroll
            for (int m = 0; m < 4; ++m)
#pragma unroll
                for (int j = 0; j < 4; ++j)
                    C[(size_t)(bm + wm * 64 + m * 16 + r0 + j) * Ddim + col] =
                        f2bf(acc[m][n][j] + bv);
        }
    } else {
        __syncthreads();   // all waves done reading K-loop LDS before reuse as T
        unsigned short* T = (unsigned short*)smem;  // [128 cols][134 rows]
#pragma unroll
        for (int n = 0; n < 4; ++n) {
            const int ccol = wn * 64 + n * 16 + cc;
            const int gcol = bn + ccol;
            const float bv = gcol < Ddim ? bph[gcol] : bg[gcol - Ddim];
#pragma unroll
            for (int m = 0; m < 4; ++m)
#pragma unroll
                for (int j = 0; j < 4; ++j)
                    T[ccol * 134 + (wm * 64 + m * 16 + r0 + j)] = f2bf(acc[m][n][j] + bv);
        }
        __syncthreads();
        const int b   = bm >> 11;
        const int bmb = bm & 2047;
        unsigned short* Co = PGTout + (size_t)b * (2 * Ddim) * Ntok;
#pragma unroll
        for (int i = 0; i < 32; ++i) {
            const int d = w * 32 + i;
            const unsigned v = *(const unsigned*)((const char*)smem + d * 268 + lane * 4);
            *(unsigned*)(Co + (size_t)(bn + d) * Ntok + bmb + lane * 2) = v;
        }
    }
}

// ---------------------------------------------------------------------------
// bf16 MFMA NT GEMM (MT / QT / y): same conflict-free layout + 3-deep loop.
// OMODE 0 fp32 out; 1 bf16 out; 3 bf16 + BN stats. SPLITK as before.
// ---------------------------------------------------------------------------
template <int OMODE, int SPLITK>
__global__ __launch_bounds__(256) void gemm_bf16(
        const unsigned short* __restrict__ Abase, long sA,
        const unsigned short* __restrict__ Bbase, long sB,
        const float* __restrict__ bias, const float* __restrict__ bias2, int Nsplit,
        void* __restrict__ Cbase, long sC,
        int M, int N, int K, float scale,
        float* __restrict__ psumG, float* __restrict__ psqG) {
    __shared__ __align__(16) char smem[49152];

    int bxi, byi, bzi;
    swz_xcd(bxi, byi, bzi);

    const int tid  = threadIdx.x;
    const int lane = tid & 63;
    const int w    = tid >> 6;
    const int wm   = w >> 1, wn = w & 1;
    const int bm = byi * 128, bn = bxi * 128;
    const int zz = bzi;

    int zb, kStart, kEnd;
    if constexpr (SPLITK > 0) {
        zb = zz / SPLITK;
        const int kl = K / SPLITK;
        kStart = (zz % SPLITK) * kl;
        kEnd = kStart + kl;
    } else {
        zb = zz; kStart = 0; kEnd = K;
    }

    const unsigned short* A = Abase + (size_t)zb * sA;
    const unsigned short* B = Bbase + (size_t)zb * sB;

    const int w8 = w * 8;
    const unsigned dOff = w * 2048 + lane * 16;
    const size_t aRow0 = (size_t)(bm + lane) * K + w8 + kStart;
    const size_t aRow1 = (size_t)(bm + 64 + lane) * K + w8 + kStart;
    const size_t bRow0 = (size_t)(bn + lane) * K + w8 + kStart;
    const size_t bRow1 = (size_t)(bn + 64 + lane) * K + w8 + kStart;

    f32x4 acc[4][4] = {};
    const int fr = lane & 15;
    const int kgOff = (lane >> 4) * 2048;

    auto bufA = [&](int p) -> char* { return smem + p * 8192; };
    auto bufB = [&](int p) -> char* { return smem + 24576 + p * 8192; };
    auto stage = [&](int p, int t) {
        const int k0 = t * 32;
        gload16(A + aRow0 + k0, bufA(p) + dOff);
        gload16(A + aRow1 + k0, bufA(p) + dOff + 1024);
        gload16(B + bRow0 + k0, bufB(p) + dOff);
        gload16(B + bRow1 + k0, bufB(p) + dOff + 1024);
    };
    auto compute = [&](int p) {
        const char* smA = bufA(p);
        const char* smB = bufB(p);
        bf16x8 fa[4], fb[4];
#pragma unroll
        for (int m = 0; m < 4; ++m)
            fa[m] = *(const bf16x8*)(smA + kgOff + (wm * 64 + m * 16 + fr) * 16);
#pragma unroll
        for (int n = 0; n < 4; ++n)
            fb[n] = *(const bf16x8*)(smB + kgOff + (wn * 64 + n * 16 + fr) * 16);
#pragma unroll
        for (int m = 0; m < 4; ++m)
#pragma unroll
            for (int n = 0; n < 4; ++n)
                acc[m][n] = __builtin_amdgcn_mfma_f32_16x16x32_bf16(fa[m], fb[n], acc[m][n], 0, 0, 0);
    };

    const int nt = (kEnd - kStart) >> 5;
    stage(0, 0); stage(1, 1);
    int p = 0;
    for (int t = 0; t < nt; ++t) {
        if (t + 1 < nt) asm volatile("s_waitcnt vmcnt(4)" ::: "memory");
        else            asm volatile("s_waitcnt vmcnt(0)" ::: "memory");
        BAR();
        if (t + 2 < nt) stage(p == 0 ? 2 : p - 1, t + 2);  // (t+2)%3
        compute(p);
        p = (p == 2) ? 0 : p + 1;
    }

    const int r0 = (lane >> 4) * 4;
    const int cc = lane & 15;
    auto getbias = [&](int gcol) -> float {
        if (!bias) return 0.0f;
        return gcol < Nsplit ? bias[gcol] : bias2[gcol - Nsplit];
    };

    if constexpr (OMODE == 0) {
        float* C = (float*)Cbase + (size_t)(SPLITK > 0 ? zz : zb) * sC;
#pragma unroll
        for (int n = 0; n < 4; ++n) {
            const int col = bn + wn * 64 + n * 16 + cc;
            const float bv = getbias(col);
#pragma unroll
            for (int m = 0; m < 4; ++m)
#pragma unroll
                for (int j = 0; j < 4; ++j)
                    C[(size_t)(bm + wm * 64 + m * 16 + r0 + j) * N + col] = acc[m][n][j] + bv;
        }
    } else if constexpr (OMODE == 1) {
        unsigned short* C = (unsigned short*)Cbase + (size_t)(SPLITK > 0 ? zz : zb) * sC;
#pragma unroll
        for (int n = 0; n < 4; ++n) {
            const int col = bn + wn * 64 + n * 16 + cc;
            const float bv = getbias(col);
#pragma unroll
            for (int m = 0; m < 4; ++m)
#pragma unroll
                for (int j = 0; j < 4; ++j)
                    C[(size_t)(bm + wm * 64 + m * 16 + r0 + j) * N + col] =
                        f2bf(acc[m][n][j] * scale + bv);
        }
    } else {
        // OMODE 3: bf16 out + deterministic per-block column stats
        unsigned short* C = (unsigned short*)Cbase + (size_t)zb * sC;
        float colS[4], colQ[4];
#pragma unroll
        for (int n = 0; n < 4; ++n) {
            const int col = bn + wn * 64 + n * 16 + cc;
            const float bv = getbias(col);
            float s = 0.f, q = 0.f;
#pragma unroll
            for (int m = 0; m < 4; ++m)
#pragma unroll
                for (int j = 0; j < 4; ++j) {
                    const float v = acc[m][n][j] + bv;
                    C[(size_t)(bm + wm * 64 + m * 16 + r0 + j) * N + col] = f2bf(v);
                    s += v; q = fmaf(v, v, q);
                }
            s += __shfl_xor(s, 16); s += __shfl_xor(s, 32);
            q += __shfl_xor(q, 16); q += __shfl_xor(q, 32);
            colS[n] = s; colQ[n] = q;
        }
        __syncthreads();   // K-loop LDS reads done in all waves before reuse
        float* sums = (float*)smem;   // [2 wm][128 cols]
        float* sqs  = sums + 256;
        if (lane < 16) {
#pragma unroll
            for (int n = 0; n < 4; ++n) {
                sums[wm * 128 + wn * 64 + n * 16 + cc] = colS[n];
                sqs [wm * 128 + wn * 64 + n * 16 + cc] = colQ[n];
            }
        }
        __syncthreads();
        if (tid < 128) {
            const int slot = zb * gridDim.y + byi;
            psumG[(size_t)slot * Cdim + bn + tid] = sums[tid] + sums[128 + tid];
            psqG [(size_t)slot * Cdim + bn + tid] = sqs[tid]  + sqs[128 + tid];
        }
    }
}

// ---------------------------------------------------------------------------
// Split-K reduce (fp32 partials): M[b][e] = bf16((1/2048)*sum_ks part[b*4+ks][e])
// 1152 blocks x 256 threads x 4 elems = 1,179,648 = Bb*Ddim*Ddim exactly.
// ---------------------------------------------------------------------------
__global__ __launch_bounds__(256) void reduce_mt(const float* __restrict__ part,
                                                 unsigned short* __restrict__ Mo) {
    const int i = blockIdx.x * 256 + threadIdx.x;
    const int e = i * 4;
    const int b = e / (Ddim * Ddim);
    const int r = e - b * (Ddim * Ddim);
    const float* base = part + (size_t)b * KSPLIT * (Ddim * Ddim) + r;
    float4 s = *(const float4*)(base);
    const float4 s1 = *(const float4*)(base + 1 * Ddim * Ddim);
    const float4 s2 = *(const float4*)(base + 2 * Ddim * Ddim);
    const float4 s3 = *(const float4*)(base + 3 * Ddim * Ddim);
    s.x += s1.x + s2.x + s3.x; s.y += s1.y + s2.y + s3.y;
    s.z += s1.z + s2.z + s3.z; s.w += s1.w + s2.w + s3.w;
    constexpr float sc = 1.0f / (float)Ntok;
    union { unsigned short u[4]; uint2 q; } o;
    o.u[0] = f2bf(s.x * sc); o.u[1] = f2bf(s.y * sc);
    o.u[2] = f2bf(s.z * sc); o.u[3] = f2bf(s.w * sc);
    *(uint2*)(Mo + e) = o.q;
}

// ---------------------------------------------------------------------------
__global__ __launch_bounds__(256) void bn_finalize(const float* __restrict__ psum,
                                                   const float* __restrict__ psq,
                                                   const float* __restrict__ gamma,
                                                   const float* __restrict__ beta,
                                                   float* __restrict__ a,
                                                   float* __restrict__ bb) {
    const int c = blockIdx.x * 256 + threadIdx.x;
    if (c >= Cdim) return;
    float s = 0.f, q = 0.f;
    for (int b = 0; b < 128; ++b) { s += psum[(size_t)b * Cdim + c]; q += psq[(size_t)b * Cdim + c]; }
    const float mean = s * (1.0f / (float)Mrows);
    const float var  = fmaf(-mean, mean, q * (1.0f / (float)Mrows));
    const float inv  = rsqrtf(var + 1e-5f);
    const float gsc  = gamma[c] * inv;
    a[c]  = gsc;
    bb[c] = fmaf(-mean, gsc, beta[c]);
}

// out = a[c]*y + bb[c] + x_h ; y bf16, out fp32
__global__ __launch_bounds__(256) void bn_apply(const unsigned short* __restrict__ y,
                                                const float* __restrict__ xh,
                                                const float* __restrict__ a,
                                                const float* __restrict__ bb,
                                                float* __restrict__ outp) {
    const size_t i = (size_t)blockIdx.x * 256 + threadIdx.x;  // uint4 index = 8 bf16
    union { uint4 q; unsigned short u[8]; } v; v.q = ((const uint4*)y)[i];
    const int c8 = (int)(i % (Cdim / 8));
    const float4 A0 = ((const float4*)a)[c8 * 2],  A1 = ((const float4*)a)[c8 * 2 + 1];
    const float4 B0 = ((const float4*)bb)[c8 * 2], B1 = ((const float4*)bb)[c8 * 2 + 1];
    const float4 X0 = ((const float4*)xh)[i * 2],  X1 = ((const float4*)xh)[i * 2 + 1];
    float4 o0, o1;
    o0.x = fmaf(A0.x, bf2f(v.u[0]), B0.x) + X0.x;
    o0.y = fmaf(A0.y, bf2f(v.u[1]), B0.y) + X0.y;
    o0.z = fmaf(A0.z, bf2f(v.u[2]), B0.z) + X0.z;
    o0.w = fmaf(A0.w, bf2f(v.u[3]), B0.w) + X0.w;
    o1.x = fmaf(A1.x, bf2f(v.u[4]), B1.x) + X1.x;
    o1.y = fmaf(A1.y, bf2f(v.u[5]), B1.y) + X1.y;
    o1.z = fmaf(A1.z, bf2f(v.u[6]), B1.z) + X1.z;
    o1.w = fmaf(A1.w, bf2f(v.u[7]), B1.w) + X1.w;
    ((float4*)outp)[i * 2]     = o0;
    ((float4*)outp)[i * 2 + 1] = o1;
}

// ---------------------------------------------------------------------------
extern "C" void kernel_launch(void* const* d_in, const int* in_sizes, int n_in,
                              void* d_out, int out_size, void* d_ws, size_t ws_size,
                              hipStream_t stream) {
    const float* x_h   = (const float*)d_in[0];
    const float* x_l   = (const float*)d_in[1];
    const float* w_g   = (const float*)d_in[2];
    const float* b_g   = (const float*)d_in[3];
    const float* w_th  = (const float*)d_in[4];
    const float* b_th  = (const float*)d_in[5];
    const float* w_ph  = (const float*)d_in[6];
    const float* b_ph  = (const float*)d_in[7];
    const float* w_out = (const float*)d_in[8];
    const float* b_out = (const float*)d_in[9];
    const float* gamma = (const float*)d_in[10];
    const float* beta  = (const float*)d_in[11];
    float* out = (float*)d_out;

    char* p = (char*)d_ws;
    unsigned short* Scr   = (unsigned short*)p; p += (size_t)Mrows * Cdim * 2;  // x_l bf16 -> fp32 partials -> Y bf16
    unsigned short* Wth16 = (unsigned short*)p; p += 294912 * 2;
    unsigned short* Wpg16 = (unsigned short*)p; p += 2 * 294912 * 2;            // [768][768]: w_phi | w_g
    unsigned short* Wout16= (unsigned short*)p; p += 294912 * 2;
    unsigned short* Tbuf  = (unsigned short*)p; p += (size_t)Mrows * Ddim * 2;  // theta bf16
    unsigned short* PGT   = (unsigned short*)p; p += (size_t)Mrows * Cdim * 2;  // [b][768][2048] phi^T|g^T
    unsigned short* Mbuf  = (unsigned short*)p; p += (size_t)Bb * Ddim * Ddim * 2;
    unsigned short* QTbuf = (unsigned short*)p; p += (size_t)Bb * Cdim * Ddim * 2;
    float* psum = (float*)p; p += (size_t)128 * Cdim * 4;
    float* psq  = (float*)p; p += (size_t)128 * Cdim * 4;
    float* avec = (float*)p; p += Cdim * 4;
    float* bvec = (float*)p; p += Cdim * 4;
    unsigned short* Xl16 = Scr;              // Scr phase 1
    float* part = (float*)Scr;               // Scr phase 2: fp32 partials [32][147456]
    unsigned short* Ybuf = Scr;              // Scr phase 3: pre-BN y bf16
    unsigned short* Xh16 = (unsigned short*)d_out;  // dead until bn_apply rewrites

    dim3 blk(256);
    const int BIG = 1 << 30;

    // weights + x_l + x_h -> bf16 (one launch)
    cast_xw<<<12864, blk, 0, stream>>>(x_l, x_h, w_th, w_ph, w_g, w_out,
                                       Xl16, Xh16, Wth16, Wpg16, Wpg16 + 294912, Wout16);
    // theta AND [phi|g] in one 1152-block launch
    gemm_inputs<<<1152, blk, 0, stream>>>(
        Xh16, Wth16, b_th, Tbuf,
        Xl16, Wpg16, b_ph, b_g, PGT);
    // split-K(4) fp32 partials: part[b*4+ks][d1][d2] = sum_{n slice} phi^T[d1][n] g^T[d2][n]
    gemm_bf16<0, KSPLIT><<<dim3(3, 3, Bb * KSPLIT), blk, 0, stream>>>(
        PGT, (long)2 * Ddim * Ntok,
        PGT + (size_t)Ddim * Ntok, (long)2 * Ddim * Ntok, nullptr, nullptr, BIG,
        part, (long)Ddim * Ddim, Ddim, Ddim, Ntok, 1.0f, nullptr, nullptr);
    reduce_mt<<<1152, blk, 0, stream>>>(part, Mbuf);
    // QT[b][c][d1] = sum_d2 w_out[c][d2] * M[b][d1][d2]
    gemm_bf16<1, 0><<<dim3(3, 6, 8), blk, 0, stream>>>(
        Wout16, 0, Mbuf, (long)Ddim * Ddim, nullptr, nullptr, BIG,
        QTbuf, (long)Cdim * Ddim, Cdim, Ddim, Ddim, 1.0f, nullptr, nullptr);
    // y = theta * QT^T + b_out -> bf16 Ybuf, fused BN column partials
    gemm_bf16<3, 0><<<dim3(6, 16, 8), blk, 0, stream>>>(
        Tbuf, (long)Ntok * Ddim, QTbuf, (long)Cdim * Ddim, b_out, nullptr, BIG,
        Ybuf, (long)Ntok * Cdim, Ntok, Cdim, Ddim, 1.0f, psum, psq);
    // BN finalize + apply + residual
    bn_finalize<<<dim3(3), blk, 0, stream>>>(psum, psq, gamma, beta, avec, bvec);
    bn_apply<<<dim3(6144), blk, 0, stream>>>(Ybuf, x_h, avec, bvec, out);
}

// Round 20
// 146.773 us; speedup vs baseline: 1.2208x; 1.2208x over previous
//
#include <hip/hip_runtime.h>

typedef short bf16x8 __attribute__((ext_vector_type(8)));
typedef float f32x4 __attribute__((ext_vector_type(4)));

constexpr int Bb = 8, Ntok = 2048, Cdim = 768, Ddim = 384, Mrows = 16384;
constexpr int KSPLIT = 4;   // MT GEMM K-slices per batch

__device__ __forceinline__ void gload16(const void* g, void* l) {
    __builtin_amdgcn_global_load_lds(
        (const __attribute__((address_space(1))) unsigned int*)g,
        (__attribute__((address_space(3))) unsigned int*)l, 16, 0, 0);
}

// Hand-rolled RNE fp32->bf16 (finite inputs only)
__device__ __forceinline__ unsigned short f2bf(float x) {
    union { float f; unsigned u; } c; c.f = x;
    const unsigned r = c.u + 0x7fffu + ((c.u >> 16) & 1u);
    return (unsigned short)(r >> 16);
}
__device__ __forceinline__ float bf2f(unsigned short u) {
    union { unsigned u; float f; } c; c.u = (unsigned)u << 16;
    return c.f;
}
__device__ __forceinline__ uint4 cvt8(const float4 a, const float4 b) {
    union { unsigned short u[8]; uint4 q; } r;
    r.u[0] = f2bf(a.x); r.u[1] = f2bf(a.y); r.u[2] = f2bf(a.z); r.u[3] = f2bf(a.w);
    r.u[4] = f2bf(b.x); r.u[5] = f2bf(b.y); r.u[6] = f2bf(b.z); r.u[7] = f2bf(b.w);
    return r.q;
}

// Single barrier per K-step (3-deep LDS). No sched_barrier pins (m141).
#define BAR() do { asm volatile("" ::: "memory"); __builtin_amdgcn_s_barrier(); \
                   asm volatile("" ::: "memory"); } while (0)

// T1 bijective XCD swizzle (bid->XCD assumed bid%8 round-robin).
__device__ __forceinline__ void swz_xcd(int& bx, int& by, int& bz) {
    const int NN = gridDim.x, NY = gridDim.y;
    const int NP = NY * gridDim.z;
    const int lin = blockIdx.x + NN * (blockIdx.y + NY * blockIdx.z);
    const int x = lin & 7, g = lin >> 3;
    const int pan = x * (NP >> 3) + g / NN;
    bx = g % NN; by = pan % NY; bz = pan / NY;
}

// ---------------------------------------------------------------------------
// LDS BANK-CONFLICT FIX (rule #21: swizzle BOTH sides or neither).
// Tile is [128 rows][4 granules of 16B]. Granule (row,ko) is stored at
// position kp = ko ^ ((row>>1)&3) within the row (byte row*64 + kp*16).
//  - staging: thread t (LDS dest linear t*16, unchanged -> m104-safe and
//    fully coalesced: same rows/cache lines, granules reordered in-row)
//    fetches global k-octet ko = (t&3) ^ ((row>>1)&3).
//  - read: fh = ((lane>>4) ^ ((fr>>1)&3))*16. 8-lane b128 groups then touch
//    all 32 banks exactly once (was 8-way conflict at stride-64B).
// ---------------------------------------------------------------------------

// fused cast: blocks 0..575 weights; 576..6719 x_l; 6720..12863 x_h
__global__ __launch_bounds__(256) void cast_xw(
        const float* __restrict__ xl, const float* __restrict__ xh,
        const float* __restrict__ s0, const float* __restrict__ s1,
        const float* __restrict__ s2, const float* __restrict__ s3,
        unsigned short* __restrict__ dxl, unsigned short* __restrict__ dxh,
        unsigned short* __restrict__ d0, unsigned short* __restrict__ d1,
        unsigned short* __restrict__ d2, unsigned short* __restrict__ d3) {
    const int b = blockIdx.x;
    if (b < 576) {
        constexpr int n8 = 294912 / 8;
        const int i = b * 256 + threadIdx.x;
        const int sel = i / n8, loc = i - sel * n8;
        const float* s = sel == 0 ? s0 : sel == 1 ? s1 : sel == 2 ? s2 : s3;
        unsigned short* d = sel == 0 ? d0 : sel == 1 ? d1 : sel == 2 ? d2 : d3;
        const float4* s4 = (const float4*)s;
        ((uint4*)d)[loc] = cvt8(s4[2 * loc], s4[2 * loc + 1]);
    } else if (b < 6720) {
        const int i = (b - 576) * 256 + threadIdx.x;
        const float4* s4 = (const float4*)xl;
        ((uint4*)dxl)[i] = cvt8(s4[2 * i], s4[2 * i + 1]);
    } else {
        const int i = (b - 6720) * 256 + threadIdx.x;
        const float4* s4 = (const float4*)xh;
        ((uint4*)dxh)[i] = cvt8(s4[2 * i], s4[2 * i + 1]);
    }
}

// ---------------------------------------------------------------------------
// FUSED input GEMMs: theta (384 blocks) + phi|g (768 blocks), one launch.
// 128x128 tile, BK=32, K=768 (nt=24). 3-deep LDS, one barrier per K-step.
// ---------------------------------------------------------------------------
__global__ __launch_bounds__(256) void gemm_inputs(
        const unsigned short* __restrict__ Xh, const unsigned short* __restrict__ Wth,
        const float* __restrict__ bth, unsigned short* __restrict__ Tout,
        const unsigned short* __restrict__ Xl, const unsigned short* __restrict__ Wpg,
        const float* __restrict__ bph, const float* __restrict__ bg,
        unsigned short* __restrict__ PGTout) {
    __shared__ __align__(16) char smem[49152];

    const int tid  = threadIdx.x;
    const int lane = tid & 63;
    const int w    = tid >> 6;
    const int wm   = w >> 1, wn = w & 1;

    const int bid = blockIdx.x;           // 0..1151
    const int x   = bid & 7;              // XCD
    const int g   = bid >> 3;             // 0..143
    const bool isTh = (g < 48);
    int bx, pan;
    if (isTh) { bx = g % 3;                 pan = x * 16 + g / 3; }
    else      { const int l = g - 48; bx = l % 6; pan = x * 16 + l / 6; }
    const int bm = pan * 128, bn = bx * 128;

    const unsigned short* A = isTh ? Xh : Xl;
    const unsigned short* B = isTh ? Wth : Wpg;
    constexpr int K = Cdim;                // 768
    constexpr int nt = K / 32;             // 24

    const int ldRow = tid >> 2;
    const int ldK   = (((tid & 3) ^ ((ldRow >> 1) & 3))) * 8;  // swizzled k-octet
    const unsigned ldsOff = tid * 16;                          // linear dest
    const size_t aOff0 = (size_t)(bm + ldRow) * K + ldK;
    const size_t aOff1 = (size_t)(bm + 64 + ldRow) * K + ldK;
    const size_t bOff0 = (size_t)(bn + ldRow) * K + ldK;
    const size_t bOff1 = (size_t)(bn + 64 + ldRow) * K + ldK;

    f32x4 acc[4][4] = {};
    const int fr = lane & 15;
    const int fh = ((lane >> 4) ^ ((fr >> 1) & 3)) * 16;       // swizzled read

    auto bufA = [&](int p) -> char* { return smem + p * 8192; };
    auto bufB = [&](int p) -> char* { return smem + 24576 + p * 8192; };
    auto stage = [&](int p, int t) {
        const int k0 = t * 32;
        gload16(A + aOff0 + k0, bufA(p) + ldsOff);
        gload16(A + aOff1 + k0, bufA(p) + 4096 + ldsOff);
        gload16(B + bOff0 + k0, bufB(p) + ldsOff);
        gload16(B + bOff1 + k0, bufB(p) + 4096 + ldsOff);
    };
    auto compute = [&](int p) {
        const char* smA = bufA(p);
        const char* smB = bufB(p);
        bf16x8 fa[4], fb[4];
#pragma unroll
        for (int m = 0; m < 4; ++m)
            fa[m] = *(const bf16x8*)(smA + (wm * 64 + m * 16 + fr) * 64 + fh);
#pragma unroll
        for (int n = 0; n < 4; ++n)
            fb[n] = *(const bf16x8*)(smB + (wn * 64 + n * 16 + fr) * 64 + fh);
#pragma unroll
        for (int m = 0; m < 4; ++m)
#pragma unroll
            for (int n = 0; n < 4; ++n)
                acc[m][n] = __builtin_amdgcn_mfma_f32_16x16x32_bf16(fa[m], fb[n], acc[m][n], 0, 0, 0);
    };

    stage(0, 0); stage(1, 1);
    int p = 0;
    for (int t = 0; t < nt; ++t) {
        if (t + 1 < nt) asm volatile("s_waitcnt vmcnt(4)" ::: "memory");
        else            asm volatile("s_waitcnt vmcnt(0)" ::: "memory");
        BAR();
        if (t + 2 < nt) stage(p == 0 ? 2 : p - 1, t + 2);  // (t+2)%3
        compute(p);
        p = (p == 2) ? 0 : p + 1;
    }

    const int r0 = (lane >> 4) * 4;
    const int cc = lane & 15;

    if (isTh) {
        unsigned short* C = Tout;
#pragma unroll
        for (int n = 0; n < 4; ++n) {
            const int col = bn + wn * 64 + n * 16 + cc;
            const float bv = bth[col];
#pragma unroll
            for (int m = 0; m < 4; ++m)
#pragma unroll
                for (int j = 0; j < 4; ++j)
                    C[(size_t)(bm + wm * 64 + m * 16 + r0 + j) * Ddim + col] =
                        f2bf(acc[m][n][j] + bv);
        }
    } else {
        __syncthreads();   // all waves done reading K-loop LDS before reuse as T
        unsigned short* T = (unsigned short*)smem;  // [128 cols][134 rows]
#pragma unroll
        for (int n = 0; n < 4; ++n) {
            const int ccol = wn * 64 + n * 16 + cc;
            const int gcol = bn + ccol;
            const float bv = gcol < Ddim ? bph[gcol] : bg[gcol - Ddim];
#pragma unroll
            for (int m = 0; m < 4; ++m)
#pragma unroll
                for (int j = 0; j < 4; ++j)
                    T[ccol * 134 + (wm * 64 + m * 16 + r0 + j)] = f2bf(acc[m][n][j] + bv);
        }
        __syncthreads();
        const int b   = bm >> 11;
        const int bmb = bm & 2047;
        unsigned short* Co = PGTout + (size_t)b * (2 * Ddim) * Ntok;
#pragma unroll
        for (int i = 0; i < 32; ++i) {
            const int d = w * 32 + i;
            const unsigned v = *(const unsigned*)((const char*)smem + d * 268 + lane * 4);
            *(unsigned*)(Co + (size_t)(bn + d) * Ntok + bmb + lane * 2) = v;
        }
    }
}

// ---------------------------------------------------------------------------
// bf16 MFMA NT GEMM (MT / QT / y): same swizzled layout + 3-deep loop.
// OMODE 0 fp32 out; 1 bf16 out; 3 bf16 + BN stats. SPLITK as before.
// ---------------------------------------------------------------------------
template <int OMODE, int SPLITK>
__global__ __launch_bounds__(256) void gemm_bf16(
        const unsigned short* __restrict__ Abase, long sA,
        const unsigned short* __restrict__ Bbase, long sB,
        const float* __restrict__ bias, const float* __restrict__ bias2, int Nsplit,
        void* __restrict__ Cbase, long sC,
        int M, int N, int K, float scale,
        float* __restrict__ psumG, float* __restrict__ psqG) {
    __shared__ __align__(16) char smem[49152];

    int bxi, byi, bzi;
    swz_xcd(bxi, byi, bzi);

    const int tid  = threadIdx.x;
    const int lane = tid & 63;
    const int w    = tid >> 6;
    const int wm   = w >> 1, wn = w & 1;
    const int bm = byi * 128, bn = bxi * 128;
    const int zz = bzi;

    int zb, kStart, kEnd;
    if constexpr (SPLITK > 0) {
        zb = zz / SPLITK;
        const int kl = K / SPLITK;
        kStart = (zz % SPLITK) * kl;
        kEnd = kStart + kl;
    } else {
        zb = zz; kStart = 0; kEnd = K;
    }

    const unsigned short* A = Abase + (size_t)zb * sA;
    const unsigned short* B = Bbase + (size_t)zb * sB;

    const int ldRow = tid >> 2;
    const int ldK   = (((tid & 3) ^ ((ldRow >> 1) & 3))) * 8;  // swizzled k-octet
    const unsigned ldsOff = tid * 16;
    const size_t aOff0 = (size_t)(bm + ldRow) * K + ldK;
    const size_t aOff1 = (size_t)(bm + 64 + ldRow) * K + ldK;
    const size_t bOff0 = (size_t)(bn + ldRow) * K + ldK;
    const size_t bOff1 = (size_t)(bn + 64 + ldRow) * K + ldK;

    f32x4 acc[4][4] = {};
    const int fr = lane & 15;
    const int fh = ((lane >> 4) ^ ((fr >> 1) & 3)) * 16;       // swizzled read

    auto bufA = [&](int p) -> char* { return smem + p * 8192; };
    auto bufB = [&](int p) -> char* { return smem + 24576 + p * 8192; };
    auto stage = [&](int p, int t) {
        const int k0 = kStart + t * 32;
        gload16(A + aOff0 + k0, bufA(p) + ldsOff);
        gload16(A + aOff1 + k0, bufA(p) + 4096 + ldsOff);
        gload16(B + bOff0 + k0, bufB(p) + ldsOff);
        gload16(B + bOff1 + k0, bufB(p) + 4096 + ldsOff);
    };
    auto compute = [&](int p) {
        const char* smA = bufA(p);
        const char* smB = bufB(p);
        bf16x8 fa[4], fb[4];
#pragma unroll
        for (int m = 0; m < 4; ++m)
            fa[m] = *(const bf16x8*)(smA + (wm * 64 + m * 16 + fr) * 64 + fh);
#pragma unroll
        for (int n = 0; n < 4; ++n)
            fb[n] = *(const bf16x8*)(smB + (wn * 64 + n * 16 + fr) * 64 + fh);
#pragma unroll
        for (int m = 0; m < 4; ++m)
#pragma unroll
            for (int n = 0; n < 4; ++n)
                acc[m][n] = __builtin_amdgcn_mfma_f32_16x16x32_bf16(fa[m], fb[n], acc[m][n], 0, 0, 0);
    };

    const int nt = (kEnd - kStart) >> 5;
    stage(0, 0); stage(1, 1);
    int p = 0;
    for (int t = 0; t < nt; ++t) {
        if (t + 1 < nt) asm volatile("s_waitcnt vmcnt(4)" ::: "memory");
        else            asm volatile("s_waitcnt vmcnt(0)" ::: "memory");
        BAR();
        if (t + 2 < nt) stage(p == 0 ? 2 : p - 1, t + 2);  // (t+2)%3
        compute(p);
        p = (p == 2) ? 0 : p + 1;
    }

    const int r0 = (lane >> 4) * 4;
    const int cc = lane & 15;
    auto getbias = [&](int gcol) -> float {
        if (!bias) return 0.0f;
        return gcol < Nsplit ? bias[gcol] : bias2[gcol - Nsplit];
    };

    if constexpr (OMODE == 0) {
        float* C = (float*)Cbase + (size_t)(SPLITK > 0 ? zz : zb) * sC;
#pragma unroll
        for (int n = 0; n < 4; ++n) {
            const int col = bn + wn * 64 + n * 16 + cc;
            const float bv = getbias(col);
#pragma unroll
            for (int m = 0; m < 4; ++m)
#pragma unroll
                for (int j = 0; j < 4; ++j)
                    C[(size_t)(bm + wm * 64 + m * 16 + r0 + j) * N + col] = acc[m][n][j] + bv;
        }
    } else if constexpr (OMODE == 1) {
        unsigned short* C = (unsigned short*)Cbase + (size_t)(SPLITK > 0 ? zz : zb) * sC;
#pragma unroll
        for (int n = 0; n < 4; ++n) {
            const int col = bn + wn * 64 + n * 16 + cc;
            const float bv = getbias(col);
#pragma unroll
            for (int m = 0; m < 4; ++m)
#pragma unroll
                for (int j = 0; j < 4; ++j)
                    C[(size_t)(bm + wm * 64 + m * 16 + r0 + j) * N + col] =
                        f2bf(acc[m][n][j] * scale + bv);
        }
    } else {
        // OMODE 3: bf16 out + deterministic per-block column stats
        unsigned short* C = (unsigned short*)Cbase + (size_t)zb * sC;
        float colS[4], colQ[4];
#pragma unroll
        for (int n = 0; n < 4; ++n) {
            const int col = bn + wn * 64 + n * 16 + cc;
            const float bv = getbias(col);
            float s = 0.f, q = 0.f;
#pragma unroll
            for (int m = 0; m < 4; ++m)
#pragma unroll
                for (int j = 0; j < 4; ++j) {
                    const float v = acc[m][n][j] + bv;
                    C[(size_t)(bm + wm * 64 + m * 16 + r0 + j) * N + col] = f2bf(v);
                    s += v; q = fmaf(v, v, q);
                }
            s += __shfl_xor(s, 16); s += __shfl_xor(s, 32);
            q += __shfl_xor(q, 16); q += __shfl_xor(q, 32);
            colS[n] = s; colQ[n] = q;
        }
        __syncthreads();   // K-loop LDS reads done in all waves before reuse
        float* sums = (float*)smem;   // [2 wm][128 cols]
        float* sqs  = sums + 256;
        if (lane < 16) {
#pragma unroll
            for (int n = 0; n < 4; ++n) {
                sums[wm * 128 + wn * 64 + n * 16 + cc] = colS[n];
                sqs [wm * 128 + wn * 64 + n * 16 + cc] = colQ[n];
            }
        }
        __syncthreads();
        if (tid < 128) {
            const int slot = zb * gridDim.y + byi;
            psumG[(size_t)slot * Cdim + bn + tid] = sums[tid] + sums[128 + tid];
            psqG [(size_t)slot * Cdim + bn + tid] = sqs[tid]  + sqs[128 + tid];
        }
    }
}

// ---------------------------------------------------------------------------
// Split-K reduce (fp32 partials): M[b][e] = bf16((1/2048)*sum_ks part[b*4+ks][e])
// 1152 blocks x 256 threads x 4 elems = 1,179,648 = Bb*Ddim*Ddim exactly.
// ---------------------------------------------------------------------------
__global__ __launch_bounds__(256) void reduce_mt(const float* __restrict__ part,
                                                 unsigned short* __restrict__ Mo) {
    const int i = blockIdx.x * 256 + threadIdx.x;
    const int e = i * 4;
    const int b = e / (Ddim * Ddim);
    const int r = e - b * (Ddim * Ddim);
    const float* base = part + (size_t)b * KSPLIT * (Ddim * Ddim) + r;
    float4 s = *(const float4*)(base);
    const float4 s1 = *(const float4*)(base + 1 * Ddim * Ddim);
    const float4 s2 = *(const float4*)(base + 2 * Ddim * Ddim);
    const float4 s3 = *(const float4*)(base + 3 * Ddim * Ddim);
    s.x += s1.x + s2.x + s3.x; s.y += s1.y + s2.y + s3.y;
    s.z += s1.z + s2.z + s3.z; s.w += s1.w + s2.w + s3.w;
    constexpr float sc = 1.0f / (float)Ntok;
    union { unsigned short u[4]; uint2 q; } o;
    o.u[0] = f2bf(s.x * sc); o.u[1] = f2bf(s.y * sc);
    o.u[2] = f2bf(s.z * sc); o.u[3] = f2bf(s.w * sc);
    *(uint2*)(Mo + e) = o.q;
}

// ---------------------------------------------------------------------------
__global__ __launch_bounds__(256) void bn_finalize(const float* __restrict__ psum,
                                                   const float* __restrict__ psq,
                                                   const float* __restrict__ gamma,
                                                   const float* __restrict__ beta,
                                                   float* __restrict__ a,
                                                   float* __restrict__ bb) {
    const int c = blockIdx.x * 256 + threadIdx.x;
    if (c >= Cdim) return;
    float s = 0.f, q = 0.f;
    for (int b = 0; b < 128; ++b) { s += psum[(size_t)b * Cdim + c]; q += psq[(size_t)b * Cdim + c]; }
    const float mean = s * (1.0f / (float)Mrows);
    const float var  = fmaf(-mean, mean, q * (1.0f / (float)Mrows));
    const float inv  = rsqrtf(var + 1e-5f);
    const float gsc  = gamma[c] * inv;
    a[c]  = gsc;
    bb[c] = fmaf(-mean, gsc, beta[c]);
}

// out = a[c]*y + bb[c] + x_h ; y bf16, out fp32
__global__ __launch_bounds__(256) void bn_apply(const unsigned short* __restrict__ y,
                                                const float* __restrict__ xh,
                                                const float* __restrict__ a,
                                                const float* __restrict__ bb,
                                                float* __restrict__ outp) {
    const size_t i = (size_t)blockIdx.x * 256 + threadIdx.x;  // uint4 index = 8 bf16
    union { uint4 q; unsigned short u[8]; } v; v.q = ((const uint4*)y)[i];
    const int c8 = (int)(i % (Cdim / 8));
    const float4 A0 = ((const float4*)a)[c8 * 2],  A1 = ((const float4*)a)[c8 * 2 + 1];
    const float4 B0 = ((const float4*)bb)[c8 * 2], B1 = ((const float4*)bb)[c8 * 2 + 1];
    const float4 X0 = ((const float4*)xh)[i * 2],  X1 = ((const float4*)xh)[i * 2 + 1];
    float4 o0, o1;
    o0.x = fmaf(A0.x, bf2f(v.u[0]), B0.x) + X0.x;
    o0.y = fmaf(A0.y, bf2f(v.u[1]), B0.y) + X0.y;
    o0.z = fmaf(A0.z, bf2f(v.u[2]), B0.z) + X0.z;
    o0.w = fmaf(A0.w, bf2f(v.u[3]), B0.w) + X0.w;
    o1.x = fmaf(A1.x, bf2f(v.u[4]), B1.x) + X1.x;
    o1.y = fmaf(A1.y, bf2f(v.u[5]), B1.y) + X1.y;
    o1.z = fmaf(A1.z, bf2f(v.u[6]), B1.z) + X1.z;
    o1.w = fmaf(A1.w, bf2f(v.u[7]), B1.w) + X1.w;
    ((float4*)outp)[i * 2]     = o0;
    ((float4*)outp)[i * 2 + 1] = o1;
}

// ---------------------------------------------------------------------------
extern "C" void kernel_launch(void* const* d_in, const int* in_sizes, int n_in,
                              void* d_out, int out_size, void* d_ws, size_t ws_size,
                              hipStream_t stream) {
    const float* x_h   = (const float*)d_in[0];
    const float* x_l   = (const float*)d_in[1];
    const float* w_g   = (const float*)d_in[2];
    const float* b_g   = (const float*)d_in[3];
    const float* w_th  = (const float*)d_in[4];
    const float* b_th  = (const float*)d_in[5];
    const float* w_ph  = (const float*)d_in[6];
    const float* b_ph  = (const float*)d_in[7];
    const float* w_out = (const float*)d_in[8];
    const float* b_out = (const float*)d_in[9];
    const float* gamma = (const float*)d_in[10];
    const float* beta  = (const float*)d_in[11];
    float* out = (float*)d_out;

    char* p = (char*)d_ws;
    unsigned short* Scr   = (unsigned short*)p; p += (size_t)Mrows * Cdim * 2;  // x_l bf16 -> fp32 partials -> Y bf16
    unsigned short* Wth16 = (unsigned short*)p; p += 294912 * 2;
    unsigned short* Wpg16 = (unsigned short*)p; p += 2 * 294912 * 2;            // [768][768]: w_phi | w_g
    unsigned short* Wout16= (unsigned short*)p; p += 294912 * 2;
    unsigned short* Tbuf  = (unsigned short*)p; p += (size_t)Mrows * Ddim * 2;  // theta bf16
    unsigned short* PGT   = (unsigned short*)p; p += (size_t)Mrows * Cdim * 2;  // [b][768][2048] phi^T|g^T
    unsigned short* Mbuf  = (unsigned short*)p; p += (size_t)Bb * Ddim * Ddim * 2;
    unsigned short* QTbuf = (unsigned short*)p; p += (size_t)Bb * Cdim * Ddim * 2;
    float* psum = (float*)p; p += (size_t)128 * Cdim * 4;
    float* psq  = (float*)p; p += (size_t)128 * Cdim * 4;
    float* avec = (float*)p; p += Cdim * 4;
    float* bvec = (float*)p; p += Cdim * 4;
    unsigned short* Xl16 = Scr;              // Scr phase 1
    float* part = (float*)Scr;               // Scr phase 2: fp32 partials [32][147456]
    unsigned short* Ybuf = Scr;              // Scr phase 3: pre-BN y bf16
    unsigned short* Xh16 = (unsigned short*)d_out;  // dead until bn_apply rewrites

    dim3 blk(256);
    const int BIG = 1 << 30;

    // weights + x_l + x_h -> bf16 (one launch)
    cast_xw<<<12864, blk, 0, stream>>>(x_l, x_h, w_th, w_ph, w_g, w_out,
                                       Xl16, Xh16, Wth16, Wpg16, Wpg16 + 294912, Wout16);
    // theta AND [phi|g] in one 1152-block launch
    gemm_inputs<<<1152, blk, 0, stream>>>(
        Xh16, Wth16, b_th, Tbuf,
        Xl16, Wpg16, b_ph, b_g, PGT);
    // split-K(4) fp32 partials: part[b*4+ks][d1][d2] = sum_{n slice} phi^T[d1][n] g^T[d2][n]
    gemm_bf16<0, KSPLIT><<<dim3(3, 3, Bb * KSPLIT), blk, 0, stream>>>(
        PGT, (long)2 * Ddim * Ntok,
        PGT + (size_t)Ddim * Ntok, (long)2 * Ddim * Ntok, nullptr, nullptr, BIG,
        part, (long)Ddim * Ddim, Ddim, Ddim, Ntok, 1.0f, nullptr, nullptr);
    reduce_mt<<<1152, blk, 0, stream>>>(part, Mbuf);
    // QT[b][c][d1] = sum_d2 w_out[c][d2] * M[b][d1][d2]
    gemm_bf16<1, 0><<<dim3(3, 6, 8), blk, 0, stream>>>(
        Wout16, 0, Mbuf, (long)Ddim * Ddim, nullptr, nullptr, BIG,
        QTbuf, (long)Cdim * Ddim, Cdim, Ddim, Ddim, 1.0f, nullptr, nullptr);
    // y = theta * QT^T + b_out -> bf16 Ybuf, fused BN column partials
    gemm_bf16<3, 0><<<dim3(6, 16, 8), blk, 0, stream>>>(
        Tbuf, (long)Ntok * Ddim, QTbuf, (long)Cdim * Ddim, b_out, nullptr, BIG,
        Ybuf, (long)Ntok * Cdim, Ntok, Cdim, Ddim, 1.0f, psum, psq);
    // BN finalize + apply + residual
    bn_finalize<<<dim3(3), blk, 0, stream>>>(psum, psq, gamma, beta, avec, bvec);
    bn_apply<<<dim3(6144), blk, 0, stream>>>(Ybuf, x_h, avec, bvec, out);
}